// Round 10
// baseline (4130.213 us; speedup 1.0000x reference)
//
#include <hip/hip_runtime.h>
#include <math.h>

// LSTM B=8192,T=512,IN=3,H=32,OUT=2 fp32.
// R10: pass-split across 2 waves, 16 REAL batch columns (no replication).
//   wave0: acc0 = AX*BX + Ah*Bh      (x-path + h_hi main)
//   wave1: acc1 = Al*Bh + Ah*Bl      (hi/lo correction terms)
//   P = acc0 + acc1 via lane-aligned LDS exchange (producer lane l ->
//   consumer lane l, no shuffles). Each wave tails the 4 units of its
//   parity half (chunk 2g+wv), writes h hi/lo to LDS in exact B-frag
//   order (b64 -> b128). 512 blocks x 128 thr = 1024 waves = 1/SIMD.
//   16 MFMA/wave/step, 2-deep chains. 2 barriers/step.
// Weights pre-scaled by -log2e (-2log2e for g) -> raw v_exp_f32.

namespace {
constexpr int   kT   = 512;
constexpr float kL2E = 1.44269504088896340736f;
}

typedef __bf16 bf16x8 __attribute__((ext_vector_type(8)));
typedef float  f32x4  __attribute__((ext_vector_type(4)));

union Frag {
    bf16x8 v;
    unsigned short u[8];
    unsigned int   d[4];
};

__device__ __forceinline__ unsigned short bf_rne(float f) {
    unsigned u = __float_as_uint(f);
    u += 0x7fffu + ((u >> 16) & 1u);
    return (unsigned short)(u >> 16);
}
__device__ __forceinline__ float bf_tof(unsigned short h) {
    return __uint_as_float((unsigned)h << 16);
}
__device__ __forceinline__ float fast_exp2(float v) { return __builtin_amdgcn_exp2f(v); }
__device__ __forceinline__ float fast_rcp(float v)  { return __builtin_amdgcn_rcpf(v); }
__device__ __forceinline__ unsigned pck(unsigned short a, unsigned short b) {
    return (unsigned)a | ((unsigned)b << 16);
}
// [lo16 = a.hi16, hi16 = b.hi16]  (bf16 truncation pack)
__device__ __forceinline__ unsigned pack_hi16(float a, float b) {
    return __builtin_amdgcn_perm(__float_as_uint(b), __float_as_uint(a), 0x07060302u);
}

#define MFMA16 __builtin_amdgcn_mfma_f32_16x16x32_bf16

extern "C" __global__ __launch_bounds__(128, 1)
void lstm_split(const float* __restrict__ x,
                const float* __restrict__ W_ih,
                const float* __restrict__ W_hh,
                const float* __restrict__ b_ih,
                const float* __restrict__ b_hh,
                const float* __restrict__ W_fc,
                const float* __restrict__ b_fc,
                float* __restrict__ out) {
    const int  tid  = threadIdx.x;
    const int  lane = tid & 63;
    const int  wv   = tid >> 6;         // 0: main passes, 1: correction passes
    const int  n    = lane & 15;        // batch column (real, 16/block)
    const int  q    = lane >> 4;        // quad
    const int  b    = blockIdx.x * 16 + n;
    const bool isW1 = (wv != 0);
    const bool isQ0 = (q == 0);
    const bool isQ1 = (q == 1);
    const unsigned short ONE = 0x3F80;  // bf16 1.0

    // LDS: acc exchange (lane-aligned), h in B-frag dword order, out partials
    __shared__ float    accX[8][64][4];   // [chunk][lane][r]  8 KB
    __shared__ unsigned hHi[16][20];      // [col][dword(unit/2)] pad 20
    __shared__ unsigned hLo[16][20];
    __shared__ float    pOut[2][16][2];

    // ---- A-frags: permuted scaled W_hh hi/lo + K-packed x/bias frag ----
    // chunk cc (g=cc>>1, pc=cc&1): A row m holds W row
    // R = 32g + 8(m>>2) + 4pc + (m&3)  =>  D row 4q+r of chunk cc is
    // gate g, unit u = 8q + 4pc + r (verified R3..R9).
    // F1 = wv ? Al : AX ; second operand always Ah.
    Frag F1[8], Ah[8];
#pragma unroll
    for (int cc = 0; cc < 8; ++cc) {
        const int   g  = cc >> 1, pc = cc & 1;
        const float s  = (g == 2) ? -2.0f * kL2E : -kL2E;
        const int   R  = 32 * g + 8 * (n >> 2) + 4 * pc + (n & 3);
        Frag Alx, AXx;
#pragma unroll
        for (int j = 0; j < 8; ++j) {
            const float w = W_hh[R * 32 + 8 * q + j] * s;
            const unsigned short hb = bf_rne(w);
            Ah[cc].u[j] = hb;
            Alx.u[j]    = bf_rne(w - bf_tof(hb));
        }
        // AX (verified R3/R9): q0 k0-2 Wx_hi, k3-5 Wx_lo, k6-7 Wx_hi[0,1];
        //                      q1 k0 Wx_hi[2], k1 bias_hi, k2 bias_lo.
        float wh[3], wl[3];
#pragma unroll
        for (int j = 0; j < 3; ++j) {
            const float w = W_ih[R * 3 + j] * s;
            const unsigned short hb = bf_rne(w);
            wh[j] = bf_tof(hb);
            wl[j] = w - wh[j];
        }
        const float bias = (b_ih[R] + b_hh[R]) * s;
        const unsigned short bh = bf_rne(bias);
#pragma unroll
        for (int j = 0; j < 8; ++j) AXx.u[j] = 0;
        if (isQ0) {
            AXx.u[0] = bf_rne(wh[0]); AXx.u[1] = bf_rne(wh[1]); AXx.u[2] = bf_rne(wh[2]);
            AXx.u[3] = bf_rne(wl[0]); AXx.u[4] = bf_rne(wl[1]); AXx.u[5] = bf_rne(wl[2]);
            AXx.u[6] = bf_rne(wh[0]); AXx.u[7] = bf_rne(wh[1]);
        } else if (isQ1) {
            AXx.u[0] = bf_rne(wh[2]);
            AXx.u[1] = bh;
            AXx.u[2] = bf_rne(bias - bf_tof(bh));
        }
#pragma unroll
        for (int j = 0; j < 4; ++j) F1[cc].d[j] = isW1 ? Alx.d[j] : AXx.d[j];
    }

    // zero h LDS (B(t=0) = 0) — both hi and lo, including pads
    for (int i = tid; i < 16 * 20; i += 128) {
        (&hHi[0][0])[i] = 0u;
        (&hLo[0][0])[i] = 0u;
    }
    __syncthreads();

    const float* xb = x + (size_t)b * kT * 3;

    float cst[4]   = {0.f, 0.f, 0.f, 0.f};
    float hfull[4] = {0.f, 0.f, 0.f, 0.f};

    // BX builder (verified R3/R9): q0 k=[xh0,xh1,xh2,xh0,xh1,xh2,xl0,xl1],
    //                              q1 k=[xl2,1,1,0...], q2/q3 = 0.
    Frag BX;
    auto buildBX = [&](float x0, float x1, float x2) {
        const unsigned short xh0 = bf_rne(x0), xh1 = bf_rne(x1), xh2 = bf_rne(x2);
        const unsigned short xl0 = bf_rne(x0 - bf_tof(xh0));
        const unsigned short xl1 = bf_rne(x1 - bf_tof(xh1));
        const unsigned short xl2 = bf_rne(x2 - bf_tof(xh2));
        const unsigned q0d0 = pck(xh0, xh1), q0d1 = pck(xh2, xh0);
        const unsigned q0d2 = pck(xh1, xh2), q0d3 = pck(xl0, xl1);
        const unsigned q1d0 = pck(xl2, ONE), q1d1 = (unsigned)ONE;
        BX.d[0] = isQ0 ? q0d0 : (isQ1 ? q1d0 : 0u);
        BX.d[1] = isQ0 ? q0d1 : (isQ1 ? q1d1 : 0u);
        BX.d[2] = isQ0 ? q0d2 : 0u;
        BX.d[3] = isQ0 ? q0d3 : 0u;
    };
    buildBX(xb[0], xb[1], xb[2]);

    for (int t = 0; t < kT; ++t) {
        // ---- read B-frags (h hi/lo of t-1) from LDS ----
        Frag Bh, Bl;
        {
            const uint4 th = *(const uint4*)&hHi[n][4 * q];
            const uint4 tl = *(const uint4*)&hLo[n][4 * q];
            Bh.d[0] = th.x; Bh.d[1] = th.y; Bh.d[2] = th.z; Bh.d[3] = th.w;
            Bl.d[0] = tl.x; Bl.d[1] = tl.y; Bl.d[2] = tl.z; Bl.d[3] = tl.w;
        }

        // ---- role-select B operands ----
        Frag B1, B2;
#pragma unroll
        for (int j = 0; j < 4; ++j) {
            B1.d[j] = isW1 ? Bh.d[j] : BX.d[j];
            B2.d[j] = isW1 ? Bl.d[j] : Bh.d[j];
        }

        // ---- 16 MFMA, 2-deep chains ----
        f32x4 acc[8];
        const f32x4 z = {0.f, 0.f, 0.f, 0.f};
#pragma unroll
        for (int cc = 0; cc < 8; ++cc) acc[cc] = MFMA16(F1[cc].v, B1.v, z, 0, 0, 0);
#pragma unroll
        for (int cc = 0; cc < 8; ++cc) acc[cc] = MFMA16(Ah[cc].v, B2.v, acc[cc], 0, 0, 0);

        // ---- hand partner its 4 chunks (lane-aligned) ----
#pragma unroll
        for (int g = 0; g < 4; ++g) {
            const int cw = 2 * g + 1 - wv;
            *(f32x4*)&accX[cw][lane][0] = acc[cw];
        }
        __syncthreads();

        // prefetch next x (fills shadow)
        const int tn = (t + 1 < kT) ? t + 1 : t;
        const float xn0 = xb[tn * 3 + 0];
        const float xn1 = xb[tn * 3 + 1];
        const float xn2 = xb[tn * 3 + 2];

        // ---- P = my kept chunk + partner's, then tail my 4 units ----
        float hv[4];
        {
            f32x4 P[4];
#pragma unroll
            for (int g = 0; g < 4; ++g) {
                const int ck = 2 * g + wv;
                const f32x4 part = *(const f32x4*)&accX[ck][lane][0];
                P[g] = acc[ck] + part;
            }
#pragma unroll
            for (int r = 0; r < 4; ++r) {
                const float Ei = fast_exp2(P[0][r]);
                const float Ef = fast_exp2(P[1][r]);
                const float Eg = fast_exp2(P[2][r]);
                const float Eo = fast_exp2(P[3][r]);
                // c = [c*(1+Ei)(1+Eg) + (1-Eg)(1+Ef)] / [(1+Ef)(1+Ei)(1+Eg)]
                const float a  = 1.0f + Ei;
                const float bb = 1.0f + Ef;
                const float g1 = 1.0f + Eg;
                const float gm = 1.0f - Eg;
                const float ag = a * g1;
                const float N  = fmaf(cst[r], ag, gm * bb);
                const float c  = N * fast_rcp(bb * ag);
                cst[r] = c;
                float Ec = fast_exp2(c * (-2.0f * kL2E));
                Ec = fminf(Ec, 1e30f);
                const float h = (1.0f - Ec) * fast_rcp((1.0f + Eo) * (1.0f + Ec));
                hfull[r] = h;
                hv[r] = h;
            }
        }

        // ---- pack h hi/lo and store in B-frag dword order ----
        // my units: u = 8q + 4wv + r  ->  dwords 4q+2wv, 4q+2wv+1
        const unsigned hh01 = pack_hi16(hv[0], hv[1]);
        const unsigned hh23 = pack_hi16(hv[2], hv[3]);
        const float l0 = hv[0] - __uint_as_float(__float_as_uint(hv[0]) & 0xFFFF0000u);
        const float l1 = hv[1] - __uint_as_float(__float_as_uint(hv[1]) & 0xFFFF0000u);
        const float l2 = hv[2] - __uint_as_float(__float_as_uint(hv[2]) & 0xFFFF0000u);
        const float l3 = hv[3] - __uint_as_float(__float_as_uint(hv[3]) & 0xFFFF0000u);
        const unsigned hl01 = pack_hi16(l0, l1);
        const unsigned hl23 = pack_hi16(l2, l3);
        *(uint2*)&hHi[n][4 * q + 2 * wv] = make_uint2(hh01, hh23);
        *(uint2*)&hLo[n][4 * q + 2 * wv] = make_uint2(hl01, hl23);
        __syncthreads();

        buildBX(xn0, xn1, xn2);
    }

    // ---- epilogue: out[b][o] = sum_u h_u W_fc[o][u] + b_fc[o] ----
    float s0 = 0.f, s1 = 0.f;
#pragma unroll
    for (int r = 0; r < 4; ++r) {
        const int u = 8 * q + 4 * wv + r;
        s0 = fmaf(hfull[r], W_fc[u], s0);
        s1 = fmaf(hfull[r], W_fc[32 + u], s1);
    }
    // sum over quads (cols fixed = n)
    s0 += __shfl_xor(s0, 16, 64); s1 += __shfl_xor(s1, 16, 64);
    s0 += __shfl_xor(s0, 32, 64); s1 += __shfl_xor(s1, 32, 64);
    if (lane < 16) {
        pOut[wv][n][0] = s0;
        pOut[wv][n][1] = s1;
    }
    __syncthreads();
    if (tid < 16) {
        out[(size_t)b * 2 + 0] = pOut[0][n][0] + pOut[1][n][0] + b_fc[0];
        out[(size_t)b * 2 + 1] = pOut[0][n][1] + pOut[1][n][1] + b_fc[1];
    }
}

extern "C" void kernel_launch(void* const* d_in, const int* in_sizes, int n_in,
                              void* d_out, int out_size, void* d_ws, size_t ws_size,
                              hipStream_t stream) {
    const float* x    = (const float*)d_in[0];
    const float* W_ih = (const float*)d_in[1];
    const float* W_hh = (const float*)d_in[2];
    const float* b_ih = (const float*)d_in[3];
    const float* b_hh = (const float*)d_in[4];
    const float* W_fc = (const float*)d_in[5];
    const float* b_fc = (const float*)d_in[6];
    float* out = (float*)d_out;

    const int batch = in_sizes[0] / (kT * 3);   // 8192
    dim3 grid(batch / 16);                      // 512 blocks
    dim3 block(128);                            // 2 waves (pass-split roles)
    hipLaunchKernelGGL(lstm_split, grid, block, 0, stream,
                       x, W_ih, W_hh, b_ih, b_hh, W_fc, b_fc, out);
}